// Round 13
// baseline (254.008 us; speedup 1.0000x reference)
//
#include <hip/hip_runtime.h>

// out[n,c,h,w] = sum_{5x5 in-bounds taps} exp(-0.5*||xyz_nbr - xyz_ctr||^2)
//                * mask_nbr * softmax[n,c,nbr]
// OOB taps have weight forced to 0, so staged/loaded slots at clamped
// addresses may hold garbage; they are always multiplied by 0.0f.
//
// R17: minimize total LDS-pipe ops. Ledger: R13 (98us, 4px b64 windows,
// w via LDS+cvts) < R16 (108us, 1px windows, reg w, 0 conflicts) -- the
// 1px windows DOUBLED per-CU LDS instructions. Currency = pipe-ops, not
// occupancy/latency (occ 18->46% x3 rounds: null).
// Design: 2px/thread = the compromise keeping BOTH properties:
//   - 50 weight VGPRs (no LDS round-trip, no cvts; R16 proved reg-w ok)
//   - windows: 3x 8B-aligned float2 per (c,row) covering 2 px
//     (1.5 LDS-inst/px-window vs R16's 3)
//   - fp32 everywhere (zero cvts), absmax ~0.0156
//   - HT=8 tile (halo overfetch 1.5x vs 2.0x), TWO 10-channel passes over
//     one staged buffer: sm_s 10x12x72 fp32 = 34.6KB -> 4 blocks/CU;
//     weights persist in registers across passes. Grid 2048 -> total
//     wave-LDS-ops HALVED vs R16.
// Dead ends confirmed: min-waves bounds (R6/R7 spill), global-fed inner
// loops (R8/R9/R11), manual reg-pipelining (R14), 1px windows (R16).
// Plain __launch_bounds__. 1D grid ONLY (2D broke graph replay in R3).

#define H_DIM 64
#define W_DIM 2048
#define C_DIM 20
#define N_DIM 8
#define HW (H_DIM * W_DIM)
#define BLOCK 256
#define HT 8               // output h-rows per block
#define PX 64              // output pixels per block
#define RS 12              // staged rows = HT + 4
#define CS 72              // staged cols = PX + 8
#define NGX 18             // float4 groups per staged row
#define CHP 10             // channels per pass
#define NJOBP (CHP * RS * NGX)   // 2160 stage jobs per pass

__global__ __launch_bounds__(BLOCK) void lcx_kernel(
    const float* __restrict__ xyz,
    const float* __restrict__ sm,
    const int*  __restrict__ mask,
    float* __restrict__ out)
{
    __shared__ float sm_s[CHP][RS][CS];     // 34.56 KB, fp32

    const int b  = blockIdx.x;              // 2048: 32 pxc x 8 htile x 8 n
    const int pc = b & 31;
    const int ht = (b >> 5) & 7;
    const int n  = b >> 8;
    const int w0 = pc << 6;
    const int h0 = ht << 3;
    const int t  = threadIdx.x;

    const float* xyzn  = xyz  + n * 3 * HW;
    const int*   maskn = mask + n * HW;
    const float* smn   = sm   + n * C_DIM * HW;
    float*       outn  = out  + n * C_DIM * HW;

    // thread mapping (both phases): hh = t>>5 in [0,8), pl = t&31,
    // pixels px0 = w0 + 2*pl, px1 = px0 + 1.
    const int hh  = t >> 5;
    const int pl  = t & 31;
    const int px0 = w0 + (pl << 1);
    const int h   = h0 + hh;

    // ---- stage pass p: 10 channels of the sm halo -> fp32 LDS ----
    auto stage = [&](int p) {
        #pragma unroll
        for (int it = 0; it < 9; ++it) {
            const int j = t + (it << 8);
            if (j < NJOBP) {
                const int grp = j % NGX;
                const int rem = j / NGX;    // cl*12 + row
                const int row = rem % RS;
                const int cl  = rem / RS;
                const int hi  = h0 - 2 + row;
                const int hic = (hi < 0) ? 0 : (hi > H_DIM - 1 ? H_DIM - 1 : hi);
                int gc = w0 - 4 + (grp << 2);   // clamped groups fully OOB
                gc = (gc < 0) ? 0 : (gc > W_DIM - 4 ? W_DIM - 4 : gc);
                *(float4*)&sm_s[cl][row][grp << 2] =
                    *(const float4*)(smn + (p * CHP + cl) * HW + hic * W_DIM + gc);
            }
        }
    };

    // ---- stage pass 0 first (loads in flight under weight math) ----
    stage(0);

    // ---- weights: 2 px x 25 taps in REGISTERS ----
    float wA[25], wB[25];
    {
        const int ctr = h * W_DIM + px0;
        const float2 cxp = *(const float2*)(xyzn + ctr);
        const float2 cyp = *(const float2*)(xyzn + HW + ctr);
        const float2 czp = *(const float2*)(xyzn + 2 * HW + ctr);
        const bool edgeblk = (pc == 0) || (pc == 31);  // block-uniform

        #pragma unroll
        for (int r = 0; r < 5; ++r) {
            const int hi = h + r - 2;
            if ((unsigned)hi >= (unsigned)H_DIM) {
                #pragma unroll
                for (int dj = 0; dj < 5; ++dj) { wA[r*5+dj] = 0.f; wB[r*5+dj] = 0.f; }
            } else {
                const int rb = hi * W_DIM;
                float vx[6], vy[6], vz[6];
                int   vm[6];
                bool  vok[6];
                if (!edgeblk) {
                    const int o = rb + px0 - 2;       // even -> 8B-aligned f2
                    #pragma unroll
                    for (int k = 0; k < 3; ++k) {
                        const float2 fx = *(const float2*)(xyzn + o + 2 * k);
                        const float2 fy = *(const float2*)(xyzn + HW + o + 2 * k);
                        const float2 fz = *(const float2*)(xyzn + 2 * HW + o + 2 * k);
                        const int2   fm = *(const int2*)(maskn + o + 2 * k);
                        vx[2*k] = fx.x; vx[2*k+1] = fx.y;
                        vy[2*k] = fy.x; vy[2*k+1] = fy.y;
                        vz[2*k] = fz.x; vz[2*k+1] = fz.y;
                        vm[2*k] = fm.x; vm[2*k+1] = fm.y;
                    }
                    #pragma unroll
                    for (int k = 0; k < 6; ++k) vok[k] = true;
                } else {
                    #pragma unroll
                    for (int k = 0; k < 6; ++k) {
                        const int col = px0 - 2 + k;
                        const bool cok = ((unsigned)col < (unsigned)W_DIM);
                        const int cc  = cok ? col : (col < 0 ? 0 : W_DIM - 1);
                        vx[k] = xyzn[rb + cc];
                        vy[k] = xyzn[HW + rb + cc];
                        vz[k] = xyzn[2 * HW + rb + cc];
                        vm[k] = maskn[rb + cc];
                        vok[k] = cok;
                    }
                }
                #pragma unroll
                for (int dj = 0; dj < 5; ++dj) {
                    // pixel A: window col dj; pixel B: window col dj+1
                    const float dxa = vx[dj] - cxp.x;
                    const float dya = vy[dj] - cyp.x;
                    const float dza = vz[dj] - czp.x;
                    const float d2a = fmaf(dxa, dxa, fmaf(dya, dya, dza * dza));
                    wA[r*5+dj] = (vok[dj] && vm[dj] != 0) ? __expf(-0.5f * d2a) : 0.0f;
                    const float dxb = vx[dj+1] - cxp.y;
                    const float dyb = vy[dj+1] - cyp.y;
                    const float dzb = vz[dj+1] - czp.y;
                    const float d2b = fmaf(dxb, dxb, fmaf(dyb, dyb, dzb * dzb));
                    wB[r*5+dj] = (vok[dj+1] && vm[dj+1] != 0) ? __expf(-0.5f * d2b) : 0.0f;
                }
            }
        }
    }
    __syncthreads();

    // ---- compute: 2 passes x 10 channels, windows from LDS ----
    // staged idx s holds global col (w0 - 4 + s); window for pixel A cols
    // [px0-2 .. px0+2] + pixel B shift = s in [2pl+2 .. 2pl+7], all-even
    // f2 reads (8B aligned), max 69 < 72.
    const int sbase = (pl << 1) + 2;
    const int octr  = h * W_DIM + px0;

    #pragma unroll
    for (int p = 0; p < 2; ++p) {
        if (p == 1) {
            __syncthreads();                // all pass-0 reads done
            stage(1);
            __syncthreads();                // pass-1 data ready
        }
        #pragma unroll 5
        for (int cl = 0; cl < CHP; ++cl) {
            float a0 = 0.0f, a1 = 0.0f, b0 = 0.0f, b1 = 0.0f;
            #pragma unroll
            for (int rt = 0; rt < 5; ++rt) {
                const float* pr = &sm_s[cl][hh + rt][sbase];
                const float2 v01 = *(const float2*)(pr);
                const float2 v23 = *(const float2*)(pr + 2);
                const float2 v45 = *(const float2*)(pr + 4);
                const float v0 = v01.x, v1 = v01.y, v2 = v23.x,
                            v3 = v23.y, v4 = v45.x, v5 = v45.y;
                a0 = fmaf(wA[rt*5+0], v0, a0);
                b0 = fmaf(wB[rt*5+0], v1, b0);
                a1 = fmaf(wA[rt*5+1], v1, a1);
                b1 = fmaf(wB[rt*5+1], v2, b1);
                a0 = fmaf(wA[rt*5+2], v2, a0);
                b0 = fmaf(wB[rt*5+2], v3, b0);
                a1 = fmaf(wA[rt*5+3], v3, a1);
                b1 = fmaf(wB[rt*5+3], v4, b1);
                a0 = fmaf(wA[rt*5+4], v4, a0);
                b0 = fmaf(wB[rt*5+4], v5, b0);
            }
            const int c = p * CHP + cl;
            *(float2*)(outn + c * HW + octr) = make_float2(a0 + a1, b0 + b1);
        }
    }
}

extern "C" void kernel_launch(void* const* d_in, const int* in_sizes, int n_in,
                              void* d_out, int out_size, void* d_ws, size_t ws_size,
                              hipStream_t stream)
{
    const float* xyz  = (const float*)d_in[0];
    const float* sm   = (const float*)d_in[1];
    const int*   mask = (const int*)d_in[2];
    float*       out  = (float*)d_out;

    const int grid = 32 * 8 * N_DIM;        // 2048 blocks, 1D ONLY

    lcx_kernel<<<grid, BLOCK, 0, stream>>>(xyz, sm, mask, out);
}